// Round 17
// baseline (74.750 us; speedup 1.0000x reference)
//
#include <hip/hip_runtime.h>
#include <hip/hip_bf16.h>

typedef _Float16 f16x8 __attribute__((ext_vector_type(8)));
typedef _Float16 f16x4 __attribute__((ext_vector_type(4)));
typedef _Float16 f16x2 __attribute__((ext_vector_type(2)));
typedef __fp16   fp16v2 __attribute__((ext_vector_type(2)));   // cvt_pkrtz return type
typedef float    f32x4 __attribute__((ext_vector_type(4)));

#define E_TOT   6572
#define E4_TOT  1643

// d_ws layout (ushort indices):
// [0,8192) W0p (16 frags) | [8192,20480) W1p16 paired |
// [20480,178208) em0h [6572][24] | [178208,257072) em1h [1643][48]   (all fp16)
#define W1P_OFF  8192
#define EM0B_OFF 20480
#define EM1B_OFF 178208
#define WS_TOT   257072

#if __has_builtin(__builtin_amdgcn_mfma_f32_16x16x16f16)
static __device__ __forceinline__ f32x4 MFMA16(f16x4 a, f16x4 b, f32x4 c) {
    return __builtin_amdgcn_mfma_f32_16x16x16f16(a, b, c, 0, 0, 0);
}
#else
static __device__ __forceinline__ f32x4 MFMA16(f16x4 a, f16x4 b, f32x4 c) {
    asm volatile("v_mfma_f32_16x16x16_f16 %0, %1, %2, %0"
                 : "+v"(c) : "v"(a), "v"(b));
    return c;
}
#endif

static __device__ __forceinline__ float clamp01(float v) {
    return __builtin_amdgcn_fmed3f(v, 0.0f, 1.0f);
}
static __device__ __forceinline__ unsigned cvt_pk_c01(float lo, float hi) {
    union { fp16v2 h; unsigned u; } r;
    r.h = __builtin_amdgcn_cvt_pkrtz(clamp01(lo), clamp01(hi));
    return r.u;
}
// packed-f16 lerp of one dword (2 elems): 2 VALU ops (v_pk_add + v_pk_fma)
static __device__ __forceinline__ unsigned lerp_h2(unsigned a, unsigned b, f16x2 p2) {
    union { unsigned u; f16x2 h; } A, B, R;
    A.u = a; B.u = b;
    R.h = A.h + p2 * (B.h - A.h);
    return R.u;
}
static __device__ __forceinline__ int bperm_i(int pt, int v) {
    return __builtin_amdgcn_ds_bpermute(pt << 2, v);
}
static __device__ __forceinline__ float bperm_f(int pt, float v) {
    union { float f; int i; } u, r;
    u.f = v;
    r.i = __builtin_amdgcn_ds_bpermute(pt << 2, u.i);
    return r.f;
}

// Feature k-order (as r14/r16):
//   k 0..43  = em1 col k      (W0 row 22+k)
//   k 44..63 = em0 col (k-44) (W0 row k-42)
// W0p: 16x16x32 f16 A-frag order, K=64:
//   frag(t,s<2), lane l, elem e <- W0[wrow(k)][n=16t+(l&15)], k = 32s+8*(l>>4)+e
// W1p16 (PAIRED x16 A-frags): pair p2 = q*6+t1, lane l, half h, e2<4
//   <- W1[k = 16*(2q+h)+4*(l>>4)+e2][n = 16t1+(l&15)]
// em0h: f16 [6572][24] (20 cols + 4 zero-pad); em1h: f16 [1643][48] (44 + 4 pad).
__global__ void pack_all(const float* __restrict__ W0, const float* __restrict__ W1,
                         const float* __restrict__ em0_w, const float* __restrict__ em1_w,
                         unsigned short* __restrict__ ws)
{
    int id = blockIdx.x * 256 + threadIdx.x;
    if (id >= WS_TOT) return;
    union { _Float16 h; unsigned short u; } cv;
    if (id < W1P_OFF) {                            // W0p: f = t*2+s, t<8, s<2
        int e = id & 7, l = (id >> 3) & 63, f = id >> 9;
        int g = l >> 4, c = l & 15;
        int s = f & 1, t = f >> 1;
        int k = s * 32 + g * 8 + e, n = t * 16 + c;
        int wrow = (k < 44) ? (22 + k) : (k - 42);  // em1-first permuted order
        cv.h = (_Float16)W0[wrow * 128 + n];
        ws[id] = cv.u;
    } else if (id < EM0B_OFF) {                    // W1p16 paired
        int id1 = id - W1P_OFF;
        int e2 = id1 & 3, h = (id1 >> 2) & 1, l = (id1 >> 3) & 63, p2 = id1 >> 9;
        int g = l >> 4, c = l & 15;
        int q = p2 / 6, t1 = p2 - 6 * q;
        int s1 = 2 * q + h;
        int k = 16 * s1 + 4 * g + e2, n = 16 * t1 + c;
        cv.h = (_Float16)W1[k * 96 + n];
        ws[id] = cv.u;
    } else if (id < EM1B_OFF) {                    // em0h [6572][24]
        int qd = id - EM0B_OFF;
        int row = qd / 24, col = qd - row * 24;
        cv.h = (_Float16)(col < 20 ? em0_w[row * 20 + col] : 0.0f);
        ws[id] = cv.u;
    } else {                                       // em1h [1643][48]
        int qd = id - EM1B_OFF;
        int row = qd / 48, col = qd - row * 48;
        cv.h = (_Float16)(col < 44 ? em1_w[row * 44 + col] : 0.0f);
        ws[id] = cv.u;
    }
}

// Swapped-operand f16 MFMA MLP; 4 waves/block (256 pts).
// NO feature LDS: each lane gathers+lerps DIRECTLY into its L0 B-frags --
// frag(mt,s) of lane (g,c) = feature cols [32s+8g,32s+8g+8) of point 16mt+c,
// which is 1 uint4-pair (em1) or two 4-col halves (em1/em0 by idx4>=11).
// BOTH W0p and W1p staged in LDS (40960 B, contiguous flat copy) -> all
// weight reads are conflict-free ds_read_b128; 3 blocks/CU.
__global__ __launch_bounds__(256, 3) void fused_mlp(
    const float* __restrict__ x, const float* __restrict__ emb,
    const float* __restrict__ W0, const float* __restrict__ b0,
    const float* __restrict__ b1,
    const float* __restrict__ W2, const float* __restrict__ b2,
    const unsigned short* __restrict__ ws,
    float* __restrict__ out, int N)
{
    __shared__ __align__(16) unsigned short wlds[20480];   // 40960 B: W0p|W1p
    const unsigned short* em0h = ws + EM0B_OFF;
    const unsigned short* em1h = ws + EM1B_OFF;
    const unsigned short* w0s = wlds;
    const unsigned short* w1s = wlds + W1P_OFF;

    // ---- stage W0p+W1p (contiguous 2560 uint4) once per block --------------
    {
        const uint4* src = (const uint4*)ws;
        uint4* dst = (uint4*)wlds;
        #pragma unroll
        for (int i = 0; i < 10; ++i)
            dst[threadIdx.x + i * 256] = src[threadIdx.x + i * 256];
    }
    __syncthreads();                               // only barrier in kernel

    const int lane = threadIdx.x & 63;
    const int wid  = threadIdx.x >> 6;             // wave 0..3
    const int g    = lane >> 4, c = lane & 15;
    const int p    = blockIdx.x * 256 + wid * 64 + lane;
    const int pc   = min(p, N - 1);

    // ---- own-point params ---------------------------------------------------
    const float t  = emb[pc];
    const int   i0 = (int)t;                       // i0 <= 6570 -> i0+1 valid
    const float pf = t - (float)i0;
    const float t4 = t * 0.25f;                    // exact
    const int   j0 = (int)t4;
    int   jb = j0;  float qf = t4 - (float)j0;
    if (j0 >= E4_TOT - 1) { jb = E4_TOT - 2; qf = 1.0f; }
    const float2 xv = *(const float2*)(x + 2 * pc);

    // ---- Phase A: gather+lerp DIRECTLY into L0 B-frags (no LDS) -------------
    f16x8 a0f[4][2];
    #pragma unroll
    for (int mt = 0; mt < 4; ++mt) {
        const int P = 16 * mt + c;                 // this frag-column's point
        const int   jbp = bperm_i(P, jb);
        const int   i0p = bperm_i(P, i0);
        const float qfp = bperm_f(P, qf);
        const float pfp = bperm_f(P, pf);
        const f16x2 q2 = {(_Float16)qfp, (_Float16)qfp};
        const f16x2 p2 = {(_Float16)pfp, (_Float16)pfp};
        // s=0 frag: feat k = 8g+e  ->  em1 cols 8g..8g+7 (uint4 row-pair)
        {
            const unsigned short* bA = em1h + jbp * 48 + g * 8;
            const uint4 r0 = *(const uint4*)(bA);
            const uint4 r1 = *(const uint4*)(bA + 48);
            union { uint4 u; f16x8 h; } F;
            F.u = make_uint4(lerp_h2(r0.x, r1.x, q2), lerp_h2(r0.y, r1.y, q2),
                             lerp_h2(r0.z, r1.z, q2), lerp_h2(r0.w, r1.w, q2));
            a0f[mt][0] = F.h;
        }
        // s=1 frag: feat k = 32+8g+e; two 4-col halves, idx4 = 8+2g+h
        //   idx4 <= 10 -> em1 cols idx4*4; idx4 >= 11 -> em0 cols (idx4-11)*4
        {
            unsigned dB[4];
            #pragma unroll
            for (int h = 0; h < 2; ++h) {
                const int idx4 = 8 + 2 * g + h;
                const bool use0 = (idx4 >= 11);
                const unsigned short* bB = use0 ? (em0h + i0p * 24 + (idx4 - 11) * 4)
                                                : (em1h + jbp * 48 + idx4 * 4);
                const int   rs = use0 ? 24 : 48;
                const f16x2 w2 = use0 ? p2 : q2;
                const uint2 r0 = *(const uint2*)(bB);
                const uint2 r1 = *(const uint2*)(bB + rs);
                dB[2*h]     = lerp_h2(r0.x, r1.x, w2);
                dB[2*h + 1] = lerp_h2(r0.y, r1.y, w2);
            }
            union { uint4 u; f16x8 h; } F;
            F.u = make_uint4(dB[0], dB[1], dB[2], dB[3]);
            a0f[mt][1] = F.h;
        }
    }

    // ---- x of this lane's column-points via lane exchange ------------------
    float xq0[4], xq1[4];
    #pragma unroll
    for (int mt = 0; mt < 4; ++mt) {
        xq0[mt] = bperm_f(16*mt + c, xv.x);
        xq1[mt] = bperm_f(16*mt + c, xv.y);
    }

    // ---- Layer 0 (16x16x32 f16, K=64, swapped): D0[out=16t+4g+r][pt=16mt+c] -
    // W0p frags from LDS (conflict-free b128). Epilogue: exact fp32 x, clamp,
    // pack -> L1 B-frags (pb), h1 never touches LDS.
    union U2S { uint2 u; f16x4 s; };
    f16x4 pb[8][4];
    #pragma unroll
    for (int tt = 0; tt < 8; ++tt) {
        f16x8 bw[2];
        #pragma unroll
        for (int s = 0; s < 2; ++s)
            bw[s] = *(const f16x8*)(w0s + ((tt*2 + s) << 9) + (lane << 3));
        const float4 b0v = *(const float4*)(b0 + tt*16 + g*4);  // b0[16t+4g+r]
        f32x4 acc[4];
        #pragma unroll
        for (int mt = 0; mt < 4; ++mt) acc[mt] = f32x4{b0v.x, b0v.y, b0v.z, b0v.w};
        #pragma unroll
        for (int s = 0; s < 2; ++s)
            #pragma unroll
            for (int mt = 0; mt < 4; ++mt)
                acc[mt] = __builtin_amdgcn_mfma_f32_16x16x32_f16(bw[s], a0f[mt][s], acc[mt], 0, 0, 0);
        const float4 wa = *(const float4*)(W0 + tt*16 + g*4);        // W0[0][n]
        const float4 wb = *(const float4*)(W0 + 128 + tt*16 + g*4);  // W0[1][n]
        const float wa_[4] = {wa.x, wa.y, wa.z, wa.w};
        const float wb_[4] = {wb.x, wb.y, wb.z, wb.w};
        #pragma unroll
        for (int mt = 0; mt < 4; ++mt) {
            float v0 = fmaf(xq0[mt], wa_[0], fmaf(xq1[mt], wb_[0], acc[mt][0]));
            float v1 = fmaf(xq0[mt], wa_[1], fmaf(xq1[mt], wb_[1], acc[mt][1]));
            float v2 = fmaf(xq0[mt], wa_[2], fmaf(xq1[mt], wb_[2], acc[mt][2]));
            float v3 = fmaf(xq0[mt], wa_[3], fmaf(xq1[mt], wb_[3], acc[mt][3]));
            U2S u2;
            u2.u = make_uint2(cvt_pk_c01(v0, v1), cvt_pk_c01(v2, v3));
            pb[tt][mt] = u2.s;                     // h1[k=16t+4g+e][pt=16mt+c]
        }
    }

    // ---- Layer 1 (16x16x16 f16, swapped) + fused W2; W1 frags from LDS -----
    float zp[4] = {0.f, 0.f, 0.f, 0.f};
    #pragma unroll
    for (int t1 = 0; t1 < 6; ++t1) {
        const float4 b1v = *(const float4*)(b1 + t1*16 + g*4);  // b1[16t1+4g+r]
        f32x4 acc[4];
        #pragma unroll
        for (int mt = 0; mt < 4; ++mt) acc[mt] = f32x4{b1v.x, b1v.y, b1v.z, b1v.w};
        #pragma unroll
        for (int q = 0; q < 4; ++q) {              // one LDS b128 = frags s1=2q,2q+1
            const f16x8 pr = *(const f16x8*)(w1s + ((q*6 + t1) << 9) + (lane << 3));
            f16x4 lo, hi;
            lo[0]=pr[0]; lo[1]=pr[1]; lo[2]=pr[2]; lo[3]=pr[3];
            hi[0]=pr[4]; hi[1]=pr[5]; hi[2]=pr[6]; hi[3]=pr[7];
            #pragma unroll
            for (int mt = 0; mt < 4; ++mt)
                acc[mt] = MFMA16(lo, pb[2*q][mt], acc[mt]);
            #pragma unroll
            for (int mt = 0; mt < 4; ++mt)
                acc[mt] = MFMA16(hi, pb[2*q + 1][mt], acc[mt]);
        }
        const float4 w2v = *(const float4*)(W2 + t1*16 + g*4);  // W2[16t1+4g+r]
        #pragma unroll
        for (int mt = 0; mt < 4; ++mt) {
            zp[mt] = fmaf(clamp01(acc[mt][0]), w2v.x, zp[mt]);
            zp[mt] = fmaf(clamp01(acc[mt][1]), w2v.y, zp[mt]);
            zp[mt] = fmaf(clamp01(acc[mt][2]), w2v.z, zp[mt]);
            zp[mt] = fmaf(clamp01(acc[mt][3]), w2v.w, zp[mt]);
        }
    }

    // ---- reduce over g-groups (4 lanes per pt-column), sigmoid, store ------
    float zr[4];
    #pragma unroll
    for (int mt = 0; mt < 4; ++mt) {
        float v = zp[mt];
        v += __shfl_xor(v, 16);
        v += __shfl_xor(v, 32);
        zr[mt] = v;                                // full z for pt=16mt+c
    }
    float z = (g == 0) ? zr[0] : (g == 1) ? zr[1] : (g == 2) ? zr[2] : zr[3];
    z += b2[0];
    z = 1.0f / (1.0f + __expf(-z));
    if (p < N) out[p] = z;                         // pt = 16g+c = lane: coalesced
}

extern "C" void kernel_launch(void* const* d_in, const int* in_sizes, int n_in,
                              void* d_out, int out_size, void* d_ws, size_t ws_size,
                              hipStream_t stream) {
    const float* x     = (const float*)d_in[0];
    const float* emb   = (const float*)d_in[1];
    const float* em0_w = (const float*)d_in[2];
    const float* em1_w = (const float*)d_in[3];
    const float* W0    = (const float*)d_in[4];
    const float* b0    = (const float*)d_in[5];
    const float* W1    = (const float*)d_in[6];
    const float* b1    = (const float*)d_in[7];
    const float* W2    = (const float*)d_in[8];
    const float* b2    = (const float*)d_in[9];
    float* out = (float*)d_out;
    const int N = in_sizes[1];

    unsigned short* ws = (unsigned short*)d_ws;    // 514144 B used

    pack_all<<<(WS_TOT + 255) / 256, 256, 0, stream>>>(W0, W1, em0_w, em1_w, ws);
    const int nb = (N + 255) / 256;
    fused_mlp<<<nb, 256, 0, stream>>>(x, emb, W0, b0, b1, W2, b2, ws, out, N);
}